// Round 2
// baseline (108.422 us; speedup 1.0000x reference)
//
#include <hip/hip_runtime.h>
#include <hip/hip_bf16.h>
#include <math.h>

#define NA 4096
#define NM 64
#define NQ 64
#define NH 64

// ws layout (floats):
//   PART = ws            [NA*16]   per-atom partials: slots c*3+a = pm[a][c], slot 9 = fpv
//   DQ   = ws + NA*16    [NA*64]   de_dq per atom
//   WDR  = ws + NA*80    [NA*256]  (-nmask^2 * dr) per (atom, m), stride-4
#define WS_FLOATS (NA * 336)

// ---------------- Kernel 1: per-atom MLP chain (1 wave / atom) ----------------
__global__ __launch_bounds__(64) void tnep_prep(
    const float* __restrict__ desc,
    const int*   __restrict__ gidx,
    const float* __restrict__ pos,
    const int*   __restrict__ Zp,
    const float* __restrict__ box,
    const float* __restrict__ amaskp,
    const float* __restrict__ nmaskp,
    const float* __restrict__ W0,
    const float* __restrict__ b0,
    const float* __restrict__ W1,
    const float* __restrict__ W0p,
    const float* __restrict__ b0p,
    const float* __restrict__ W1p,
    const float* __restrict__ b1p,
    float* __restrict__ ws)
{
    const int n    = blockIdx.x;
    const int lane = threadIdx.x;
    const int z    = Zp[n];
    const float amask = amaskp[n];

    float* PART = ws;
    float* DQ   = ws + NA * 16;
    float* WDR  = ws + NA * 80;

    __shared__ float sdesc[NQ];
    __shared__ float sW0[NQ * 65];
    __shared__ float sde_da[NH];

    sdesc[lane] = desc[n * NQ + lane];

    // Stage W0[z] (16 KB) into LDS, padded stride 65.
    const float4* W0v = reinterpret_cast<const float4*>(W0 + (size_t)z * NQ * NH);
#pragma unroll
    for (int i = 0; i < 16; ++i) {
        float4 v = W0v[i * 64 + lane];
        int q  = 4 * i + (lane >> 4);
        int h0 = 4 * (lane & 15);
        float* p = &sW0[q * 65 + h0];
        p[0] = v.x; p[1] = v.y; p[2] = v.z; p[3] = v.w;
    }

    // Per-pair minimal-image displacement scalars (lane = m) -> global.
    {
        int g = gidx[n * NM + lane];
        float Lx = box[0], Ly = box[4], Lz = box[8];
        float dx = pos[g * 3 + 0] - pos[n * 3 + 0];
        float dy = pos[g * 3 + 1] - pos[n * 3 + 1];
        float dz = pos[g * 3 + 2] - pos[n * 3 + 2];
        dx -= Lx * rintf(dx * (1.0f / Lx));   // rintf = round-half-even = jnp.round
        dy -= Ly * rintf(dy * (1.0f / Ly));
        dz -= Lz * rintf(dz * (1.0f / Lz));
        float nm = nmaskp[n * NM + lane];
        float w  = -nm * nm;
        float4 wd = make_float4(w * dx, w * dy, w * dz, 0.0f);
        *reinterpret_cast<float4*>(WDR + n * 256 + lane * 4) = wd;
    }
    __syncthreads();

    // Forward pass, tensor + pol ANN fused (lane = h).
    float a_t = b0 [z * NH + lane];
    float a_p = b0p[z * NH + lane];
    const float* W0prow = W0p + (size_t)z * NQ * NH;
#pragma unroll 8
    for (int q = 0; q < NQ; ++q) {
        float d = sdesc[q];
        a_t = fmaf(d, sW0[q * 65 + lane], a_t);
        a_p = fmaf(d, W0prow[q * NH + lane], a_p);   // small, L2-cached
    }
    float hT = tanhf(a_t) * amask;
    float hP = tanhf(a_p) * amask;
    sde_da[lane] = (1.0f - hT * hT) * W1[z * NH + lane];
    float fp = hP * W1p[z * NH + lane];
#pragma unroll
    for (int s = 1; s < 64; s <<= 1) fp += __shfl_xor(fp, s, 64);
    __syncthreads();

    // Backward: de_dq[q] = sum_h de_da[h] * W0[z][q][h]   (lane = q).
    float dq = 0.0f;
#pragma unroll 8
    for (int h = 0; h < NH; ++h)
        dq = fmaf(sde_da[h], sW0[lane * 65 + h], dq);
    DQ[n * 64 + lane] = dq;

    if (lane == 0) PART[n * 16 + 9] = (fp + b1p[0]) * amask;
}

// ------------- Kernel 2: gradient streaming (4 waves / atom, tiny LDS) -------------
__global__ __launch_bounds__(256) void tnep_stream(
    const float* __restrict__ grad,
    float* __restrict__ ws)
{
    const int n    = blockIdx.x;
    const int tid  = threadIdx.x;
    const int w    = tid >> 6;
    const int lane = tid & 63;

    float* PART = ws;
    const float* DQ  = ws + NA * 16;
    const float* WDR = ws + NA * 80;

    __shared__ float swdr[NM * 4];
    __shared__ float sacc[4][9];

    swdr[tid] = WDR[n * 256 + tid];                    // 1 KB stage
    float4 dq4 = *reinterpret_cast<const float4*>(DQ + n * 64 + 4 * (lane & 15));
    __syncthreads();

    // lane = msub*16 + q4. Each 16-lane cluster owns one m-row; c unrolled
    // compile-time so all accumulator indices are static (no scratch).
    const int msub = lane >> 4;
    const int q4   = lane & 15;
    float acc[3][3] = {{0.f,0.f,0.f},{0.f,0.f,0.f},{0.f,0.f,0.f}};

    const int m0 = w * 16;
    const float4* gbase = reinterpret_cast<const float4*>(grad)
                          + ((size_t)n * NM + m0) * 48 + msub * 48 + q4;
#pragma unroll
    for (int gset = 0; gset < 4; ++gset) {             // 4 m's per set
        const float4* gp = gbase + gset * 192;
        const int m = m0 + gset * 4 + msub;
        float wd0 = swdr[m * 4 + 0];
        float wd1 = swdr[m * 4 + 1];
        float wd2 = swdr[m * 4 + 2];
#pragma unroll
        for (int c = 0; c < 3; ++c) {
            float4 g4 = gp[c * 16];
            float s = fmaf(dq4.x, g4.x, fmaf(dq4.y, g4.y,
                      fmaf(dq4.z, g4.z, dq4.w * g4.w)));
            // sum over the 16 q-lanes of this cluster
#pragma unroll
            for (int t = 1; t < 16; t <<= 1) s += __shfl_xor(s, t, 64);
            acc[0][c] = fmaf(s, wd0, acc[0][c]);
            acc[1][c] = fmaf(s, wd1, acc[1][c]);
            acc[2][c] = fmaf(s, wd2, acc[2][c]);
        }
    }

    // Lanes within a cluster hold identical acc; sum one per cluster.
#pragma unroll
    for (int a = 0; a < 3; ++a)
#pragma unroll
        for (int c = 0; c < 3; ++c) {
            float v = acc[a][c];
            v += __shfl_xor(v, 16, 64);
            v += __shfl_xor(v, 32, 64);
            acc[a][c] = v;
        }
    if (lane == 0) {
#pragma unroll
        for (int a = 0; a < 3; ++a)
#pragma unroll
            for (int c = 0; c < 3; ++c) sacc[w][c * 3 + a] = acc[a][c];
    }
    __syncthreads();
    if (tid < 9)
        PART[n * 16 + tid] = sacc[0][tid] + sacc[1][tid] + sacc[2][tid] + sacc[3][tid];
}

// ---------------- Kernel 3: final deterministic reduction ----------------
__global__ __launch_bounds__(256) void tnep_reduce(const float* __restrict__ ws,
                                                   float* __restrict__ out)
{
    __shared__ float s[256];
    int t = threadIdx.x;
    int k = t & 15;
    int r = t >> 4;
    float v = 0.f;
    if (k < 10) {
        for (int b = r; b < NA; b += 16) v += ws[b * 16 + k];
    }
    s[t] = v;
    __syncthreads();
    if (t < 16) {
        float tot = 0.f;
#pragma unroll
        for (int j = 0; j < 16; ++j) tot += s[j * 16 + t];
        s[t] = tot;
    }
    __syncthreads();
    if (t == 0) {
        float S = s[9];
        out[0] = s[0] + S;
        out[1] = s[4] + S;
        out[2] = s[8] + S;
        out[3] = s[3];
        out[4] = s[7];
        out[5] = s[2];
    }
}

// ---------------- Fallback (tiny ws): original monolithic kernel ----------------
__global__ __launch_bounds__(64) void tnep_mono(
    const float* __restrict__ desc,
    const float* __restrict__ grad,
    const int*   __restrict__ gidx,
    const float* __restrict__ pos,
    const int*   __restrict__ Zp,
    const float* __restrict__ box,
    const float* __restrict__ amaskp,
    const float* __restrict__ nmaskp,
    const float* __restrict__ W0,
    const float* __restrict__ b0,
    const float* __restrict__ W1,
    const float* __restrict__ W0p,
    const float* __restrict__ b0p,
    const float* __restrict__ W1p,
    const float* __restrict__ b1p,
    float* __restrict__ out)
{
    const int n    = blockIdx.x;
    const int lane = threadIdx.x;
    const int z    = Zp[n];
    const float amask = amaskp[n];

    __shared__ float sdesc[NQ];
    __shared__ float sW0[NQ * 65];
    __shared__ float sde_da[NH];
    __shared__ float sde_dq[NQ];
    __shared__ float sdr[NM * 4];

    sdesc[lane] = desc[n * NQ + lane];
    const float4* W0v = reinterpret_cast<const float4*>(W0 + (size_t)z * NQ * NH);
#pragma unroll
    for (int i = 0; i < 16; ++i) {
        float4 v = W0v[i * 64 + lane];
        int q  = 4 * i + (lane >> 4);
        int h0 = 4 * (lane & 15);
        float* p = &sW0[q * 65 + h0];
        p[0] = v.x; p[1] = v.y; p[2] = v.z; p[3] = v.w;
    }
    {
        int g = gidx[n * NM + lane];
        float Lx = box[0], Ly = box[4], Lz = box[8];
        float dx = pos[g * 3 + 0] - pos[n * 3 + 0];
        float dy = pos[g * 3 + 1] - pos[n * 3 + 1];
        float dz = pos[g * 3 + 2] - pos[n * 3 + 2];
        dx -= Lx * rintf(dx * (1.0f / Lx));
        dy -= Ly * rintf(dy * (1.0f / Ly));
        dz -= Lz * rintf(dz * (1.0f / Lz));
        float nm = nmaskp[n * NM + lane];
        float w  = -nm * nm;
        sdr[lane * 4 + 0] = w * dx;
        sdr[lane * 4 + 1] = w * dy;
        sdr[lane * 4 + 2] = w * dz;
        sdr[lane * 4 + 3] = 0.0f;
    }
    __syncthreads();

    float a_t = b0 [z * NH + lane];
    float a_p = b0p[z * NH + lane];
    const float* W0prow = W0p + (size_t)z * NQ * NH;
#pragma unroll 8
    for (int q = 0; q < NQ; ++q) {
        float d = sdesc[q];
        a_t = fmaf(d, sW0[q * 65 + lane], a_t);
        a_p = fmaf(d, W0prow[q * NH + lane], a_p);
    }
    float hT = tanhf(a_t) * amask;
    float hP = tanhf(a_p) * amask;
    sde_da[lane] = (1.0f - hT * hT) * W1[z * NH + lane];
    float fp = hP * W1p[z * NH + lane];
#pragma unroll
    for (int s = 1; s < 64; s <<= 1) fp += __shfl_xor(fp, s, 64);
    __syncthreads();

    float dq = 0.0f;
#pragma unroll 8
    for (int h = 0; h < NH; ++h)
        dq = fmaf(sde_da[h], sW0[lane * 65 + h], dq);
    sde_dq[lane] = dq;
    __syncthreads();

    const int c  = lane >> 4;
    const int qg = lane & 15;
    float4 dq4 = *reinterpret_cast<const float4*>(&sde_dq[4 * qg]);
    float acc0 = 0.f, acc1 = 0.f, acc2 = 0.f;
    if (c < 3) {
        const float4* gp = reinterpret_cast<const float4*>(grad + (size_t)n * NM * 3 * NQ)
                           + c * 16 + qg;
#pragma unroll 4
        for (int m = 0; m < NM; ++m) {
            float4 g4 = gp[m * 48];
            float s = fmaf(dq4.x, g4.x, fmaf(dq4.y, g4.y, fmaf(dq4.z, g4.z, dq4.w * g4.w)));
            float4 d4 = *reinterpret_cast<const float4*>(&sdr[m * 4]);
            acc0 = fmaf(d4.x, s, acc0);
            acc1 = fmaf(d4.y, s, acc1);
            acc2 = fmaf(d4.z, s, acc2);
        }
    }
#pragma unroll
    for (int s = 1; s < 16; s <<= 1) {
        acc0 += __shfl_xor(acc0, s, 64);
        acc1 += __shfl_xor(acc1, s, 64);
        acc2 += __shfl_xor(acc2, s, 64);
    }
    float fpv = (fp + b1p[0]) * amask;
    if (qg == 0 && c < 3) {
        const int map[9] = {0, -1, 5, 3, 1, -1, -1, 4, 2};
        int m0 = map[c * 3 + 0], m1 = map[c * 3 + 1], m2 = map[c * 3 + 2];
        if (m0 >= 0) atomicAdd(out + m0, acc0);
        if (m1 >= 0) atomicAdd(out + m1, acc1);
        if (m2 >= 0) atomicAdd(out + m2, acc2);
    }
    if (lane == 0) {
        atomicAdd(out + 0, fpv);
        atomicAdd(out + 1, fpv);
        atomicAdd(out + 2, fpv);
    }
}

__global__ void tnep_zero(float* out)
{
    if (threadIdx.x < 6) out[threadIdx.x] = 0.f;
}

extern "C" void kernel_launch(void* const* d_in, const int* in_sizes, int n_in,
                              void* d_out, int out_size, void* d_ws, size_t ws_size,
                              hipStream_t stream)
{
    const float* desc  = (const float*)d_in[0];
    const float* grad  = (const float*)d_in[1];
    const int*   gidx  = (const int*)  d_in[2];
    const float* pos   = (const float*)d_in[3];
    const int*   Zp    = (const int*)  d_in[4];
    const float* box   = (const float*)d_in[5];
    const float* amask = (const float*)d_in[6];
    const float* nmask = (const float*)d_in[7];
    const float* W0    = (const float*)d_in[8];
    const float* b0    = (const float*)d_in[9];
    const float* W1    = (const float*)d_in[10];
    // d_in[11] = b1 (unused by reference)
    const float* W0p   = (const float*)d_in[12];
    const float* b0p   = (const float*)d_in[13];
    const float* W1p   = (const float*)d_in[14];
    const float* b1p   = (const float*)d_in[15];
    float* out = (float*)d_out;
    float* ws  = (float*)d_ws;

    if (ws_size >= (size_t)WS_FLOATS * sizeof(float)) {
        tnep_prep<<<NA, 64, 0, stream>>>(desc, gidx, pos, Zp, box, amask, nmask,
                                         W0, b0, W1, W0p, b0p, W1p, b1p, ws);
        tnep_stream<<<NA, 256, 0, stream>>>(grad, ws);
        tnep_reduce<<<1, 256, 0, stream>>>(ws, out);
    } else {
        tnep_zero<<<1, 64, 0, stream>>>(out);
        tnep_mono<<<NA, 64, 0, stream>>>(desc, grad, gidx, pos, Zp, box, amask, nmask,
                                         W0, b0, W1, W0p, b0p, W1p, b1p, out);
    }
}

// Round 3
// 47.382 us; speedup vs baseline: 2.2882x; 2.2882x over previous
//
#include <hip/hip_runtime.h>
#include <hip/hip_bf16.h>
#include <math.h>

#define NA 4096
#define NM 64
#define NQ 64
#define NH 64

// ws layout (floats): PARTT[slot][NA], slot = a*3+c for pm[a][c], slot 9 = fpv.
#define WS_FLOATS (10 * NA)

// ---------------- Main fused kernel: one atom per 256-thread block ----------------
// Waves: 0 = tensor ANN fwd/bwd, 1 = displacement scalars, 2 = pol ANN, 3 = idle
// during MLP; ALL 4 waves stream the 48 KB gradients with a shfl-free inner loop.
__global__ __launch_bounds__(256) void tnep_main(
    const float* __restrict__ desc,
    const float* __restrict__ grad,
    const int*   __restrict__ gidx,
    const float* __restrict__ pos,
    const int*   __restrict__ Zp,
    const float* __restrict__ box,
    const float* __restrict__ amaskp,
    const float* __restrict__ nmaskp,
    const float* __restrict__ W0,
    const float* __restrict__ b0,
    const float* __restrict__ W1,
    const float* __restrict__ W0p,
    const float* __restrict__ b0p,
    const float* __restrict__ W1p,
    const float* __restrict__ b1p,
    float* __restrict__ ws)
{
    const int n    = blockIdx.x;
    const int tid  = threadIdx.x;
    const int w    = tid >> 6;
    const int lane = tid & 63;
    const int z    = Zp[n];

    __shared__ float sW0[NQ * 65];     // padded: fwd (row bcast) & bwd (col) conflict-free
    __shared__ float sdesc[NQ];
    __shared__ float sde_da[NH];
    __shared__ float sde_dq[NQ];
    __shared__ float swdr[NM * 4];
    __shared__ float sacc[4][12];

    // Cooperative stage of W0[z] (16 KB), all 256 threads.
    const float4* W0v = reinterpret_cast<const float4*>(W0 + (size_t)z * NQ * NH);
#pragma unroll
    for (int i = 0; i < 4; ++i) {
        int f = i * 256 + tid;
        float4 v = W0v[f];
        int q  = f >> 4;
        int h0 = (f & 15) * 4;
        float* p = &sW0[q * 65 + h0];
        p[0] = v.x; p[1] = v.y; p[2] = v.z; p[3] = v.w;
    }
    if (w == 0) sdesc[lane] = desc[n * NQ + lane];
    if (w == 1) {
        // Minimal-image displacement scalars, -nmask^2 folded in (lane = m).
        int g = gidx[n * NM + lane];
        float Lx = box[0], Ly = box[4], Lz = box[8];
        float dx = pos[g * 3 + 0] - pos[n * 3 + 0];
        float dy = pos[g * 3 + 1] - pos[n * 3 + 1];
        float dz = pos[g * 3 + 2] - pos[n * 3 + 2];
        dx -= Lx * rintf(dx * (1.0f / Lx));   // rintf = round-half-even = jnp.round
        dy -= Ly * rintf(dy * (1.0f / Ly));
        dz -= Lz * rintf(dz * (1.0f / Lz));
        float nm = nmaskp[n * NM + lane];
        float wt = -nm * nm;
        swdr[lane * 4 + 0] = wt * dx;
        swdr[lane * 4 + 1] = wt * dy;
        swdr[lane * 4 + 2] = wt * dz;
        swdr[lane * 4 + 3] = 0.0f;
    }
    __syncthreads();   // sW0, sdesc, swdr ready

    if (w == 0) {
        // Tensor ANN forward (lane = h).
        float amask = amaskp[n];
        float a_t = b0[z * NH + lane];
#pragma unroll 8
        for (int q = 0; q < NQ; ++q)
            a_t = fmaf(sdesc[q], sW0[q * 65 + lane], a_t);
        float hT = tanhf(a_t) * amask;
        sde_da[lane] = (1.0f - hT * hT) * W1[z * NH + lane];
    } else if (w == 2) {
        // Pol ANN, fully independent of LDS (desc read via uniform global loads).
        float amask = amaskp[n];
        float a_p = b0p[z * NH + lane];
        const float* W0prow = W0p + (size_t)z * NQ * NH;
        const float* drow   = desc + (size_t)n * NQ;
#pragma unroll 8
        for (int q = 0; q < NQ; ++q)
            a_p = fmaf(drow[q], W0prow[q * NH + lane], a_p);
        float hP = tanhf(a_p) * amask;
        float fp = hP * W1p[z * NH + lane];
#pragma unroll
        for (int s = 1; s < 64; s <<= 1) fp += __shfl_xor(fp, s, 64);
        if (lane == 0) ws[9 * NA + n] = (fp + b1p[0]) * amask;
    }
    __syncthreads();   // sde_da ready

    if (w == 0) {
        // Backward: de_dq[q] = sum_h de_da[h] * W0[q][h]  (lane = q).
        float dq = 0.0f;
#pragma unroll 8
        for (int h = 0; h < NH; ++h)
            dq = fmaf(sde_da[h], sW0[lane * 65 + h], dq);
        sde_dq[lane] = dq;
    }
    __syncthreads();   // sde_dq ready

    // ---- Streaming phase: wave w owns m in [w*16, w*16+16). ----
    // lane = msub*16 + q4; per-lane partial over its q-slice; NO inner shfl:
    // acc[a][c] summed across all 64 lanes once at the end.
    const int msub = lane >> 4;
    const int q4   = lane & 15;
    float4 dq4 = *reinterpret_cast<const float4*>(&sde_dq[4 * q4]);
    float acc[3][3] = {{0.f,0.f,0.f},{0.f,0.f,0.f},{0.f,0.f,0.f}};

    const int m0 = w * 16;
    const float4* gbase = reinterpret_cast<const float4*>(grad)
                          + ((size_t)n * NM + m0) * 48 + msub * 48 + q4;
#pragma unroll
    for (int gset = 0; gset < 4; ++gset) {
        const float4* gp = gbase + gset * 192;
        const int m = m0 + gset * 4 + msub;
        float wd0 = swdr[m * 4 + 0];
        float wd1 = swdr[m * 4 + 1];
        float wd2 = swdr[m * 4 + 2];
#pragma unroll
        for (int c = 0; c < 3; ++c) {
            float4 g4 = gp[c * 16];
            float s = fmaf(dq4.x, g4.x, fmaf(dq4.y, g4.y,
                      fmaf(dq4.z, g4.z, dq4.w * g4.w)));
            acc[0][c] = fmaf(s, wd0, acc[0][c]);
            acc[1][c] = fmaf(s, wd1, acc[1][c]);
            acc[2][c] = fmaf(s, wd2, acc[2][c]);
        }
    }

    // One 64-lane reduction per wave, then cross-wave via LDS.
#pragma unroll
    for (int a = 0; a < 3; ++a)
#pragma unroll
        for (int c = 0; c < 3; ++c) {
            float v = acc[a][c];
#pragma unroll
            for (int s = 1; s < 64; s <<= 1) v += __shfl_xor(v, s, 64);
            if (lane == 0) sacc[w][a * 3 + c] = v;
        }
    __syncthreads();
    if (tid < 9)
        ws[tid * NA + n] = sacc[0][tid] + sacc[1][tid] + sacc[2][tid] + sacc[3][tid];
}

// ---------------- Final reduction: 10 waves, one slot each, coalesced ----------------
__global__ __launch_bounds__(640) void tnep_reduce(const float* __restrict__ ws,
                                                   float* __restrict__ out)
{
    __shared__ float sred[10];
    const int w    = threadIdx.x >> 6;
    const int lane = threadIdx.x & 63;

    const float4* p = reinterpret_cast<const float4*>(ws + (size_t)w * NA);
    float s = 0.f;
#pragma unroll
    for (int i = 0; i < 16; ++i) {
        float4 v = p[lane + 64 * i];
        s += (v.x + v.y) + (v.z + v.w);
    }
#pragma unroll
    for (int t = 1; t < 64; t <<= 1) s += __shfl_xor(s, t, 64);
    if (lane == 0) sred[w] = s;
    __syncthreads();
    if (threadIdx.x == 0) {
        float S = sred[9];
        out[0] = sred[0] + S;   // pm00 + scalar
        out[1] = sred[4] + S;   // pm11 + scalar
        out[2] = sred[8] + S;   // pm22 + scalar
        out[3] = sred[1];       // pm01
        out[4] = sred[5];       // pm12
        out[5] = sred[6];       // pm20
    }
}

// ---------------- Fallback (tiny ws): monolithic with atomics ----------------
__global__ __launch_bounds__(64) void tnep_mono(
    const float* __restrict__ desc,
    const float* __restrict__ grad,
    const int*   __restrict__ gidx,
    const float* __restrict__ pos,
    const int*   __restrict__ Zp,
    const float* __restrict__ box,
    const float* __restrict__ amaskp,
    const float* __restrict__ nmaskp,
    const float* __restrict__ W0,
    const float* __restrict__ b0,
    const float* __restrict__ W1,
    const float* __restrict__ W0p,
    const float* __restrict__ b0p,
    const float* __restrict__ W1p,
    const float* __restrict__ b1p,
    float* __restrict__ out)
{
    const int n    = blockIdx.x;
    const int lane = threadIdx.x;
    const int z    = Zp[n];
    const float amask = amaskp[n];

    __shared__ float sdesc[NQ];
    __shared__ float sW0[NQ * 65];
    __shared__ float sde_da[NH];
    __shared__ float sde_dq[NQ];
    __shared__ float sdr[NM * 4];

    sdesc[lane] = desc[n * NQ + lane];
    const float4* W0v = reinterpret_cast<const float4*>(W0 + (size_t)z * NQ * NH);
#pragma unroll
    for (int i = 0; i < 16; ++i) {
        float4 v = W0v[i * 64 + lane];
        int q  = 4 * i + (lane >> 4);
        int h0 = 4 * (lane & 15);
        float* p = &sW0[q * 65 + h0];
        p[0] = v.x; p[1] = v.y; p[2] = v.z; p[3] = v.w;
    }
    {
        int g = gidx[n * NM + lane];
        float Lx = box[0], Ly = box[4], Lz = box[8];
        float dx = pos[g * 3 + 0] - pos[n * 3 + 0];
        float dy = pos[g * 3 + 1] - pos[n * 3 + 1];
        float dz = pos[g * 3 + 2] - pos[n * 3 + 2];
        dx -= Lx * rintf(dx * (1.0f / Lx));
        dy -= Ly * rintf(dy * (1.0f / Ly));
        dz -= Lz * rintf(dz * (1.0f / Lz));
        float nm = nmaskp[n * NM + lane];
        float wt = -nm * nm;
        sdr[lane * 4 + 0] = wt * dx;
        sdr[lane * 4 + 1] = wt * dy;
        sdr[lane * 4 + 2] = wt * dz;
        sdr[lane * 4 + 3] = 0.0f;
    }
    __syncthreads();

    float a_t = b0 [z * NH + lane];
    float a_p = b0p[z * NH + lane];
    const float* W0prow = W0p + (size_t)z * NQ * NH;
#pragma unroll 8
    for (int q = 0; q < NQ; ++q) {
        float d = sdesc[q];
        a_t = fmaf(d, sW0[q * 65 + lane], a_t);
        a_p = fmaf(d, W0prow[q * NH + lane], a_p);
    }
    float hT = tanhf(a_t) * amask;
    float hP = tanhf(a_p) * amask;
    sde_da[lane] = (1.0f - hT * hT) * W1[z * NH + lane];
    float fp = hP * W1p[z * NH + lane];
#pragma unroll
    for (int s = 1; s < 64; s <<= 1) fp += __shfl_xor(fp, s, 64);
    __syncthreads();

    float dq = 0.0f;
#pragma unroll 8
    for (int h = 0; h < NH; ++h)
        dq = fmaf(sde_da[h], sW0[lane * 65 + h], dq);
    sde_dq[lane] = dq;
    __syncthreads();

    const int msub = lane >> 4;
    const int q4   = lane & 15;
    float4 dq4 = *reinterpret_cast<const float4*>(&sde_dq[4 * q4]);
    float acc[3][3] = {{0.f,0.f,0.f},{0.f,0.f,0.f},{0.f,0.f,0.f}};
    const float4* gbase = reinterpret_cast<const float4*>(grad)
                          + (size_t)n * NM * 48 + msub * 48 + q4;
#pragma unroll
    for (int gset = 0; gset < 16; ++gset) {
        const float4* gp = gbase + gset * 192;
        const int m = gset * 4 + msub;
        float wd0 = sdr[m * 4 + 0];
        float wd1 = sdr[m * 4 + 1];
        float wd2 = sdr[m * 4 + 2];
#pragma unroll
        for (int c = 0; c < 3; ++c) {
            float4 g4 = gp[c * 16];
            float s = fmaf(dq4.x, g4.x, fmaf(dq4.y, g4.y, fmaf(dq4.z, g4.z, dq4.w * g4.w)));
            acc[0][c] = fmaf(s, wd0, acc[0][c]);
            acc[1][c] = fmaf(s, wd1, acc[1][c]);
            acc[2][c] = fmaf(s, wd2, acc[2][c]);
        }
    }
    float fpv = (fp + b1p[0]) * amask;
#pragma unroll
    for (int a = 0; a < 3; ++a)
#pragma unroll
        for (int c = 0; c < 3; ++c) {
            float v = acc[a][c];
#pragma unroll
            for (int s = 1; s < 64; s <<= 1) v += __shfl_xor(v, s, 64);
            acc[a][c] = v;
        }
    if (lane == 0) {
        // out mapping: 0:pm00 1:pm11 2:pm22 3:pm01 4:pm12 5:pm20
        atomicAdd(out + 0, acc[0][0] + fpv);
        atomicAdd(out + 1, acc[1][1] + fpv);
        atomicAdd(out + 2, acc[2][2] + fpv);
        atomicAdd(out + 3, acc[0][1]);
        atomicAdd(out + 4, acc[1][2]);
        atomicAdd(out + 5, acc[2][0]);
    }
}

__global__ void tnep_zero(float* out)
{
    if (threadIdx.x < 6) out[threadIdx.x] = 0.f;
}

extern "C" void kernel_launch(void* const* d_in, const int* in_sizes, int n_in,
                              void* d_out, int out_size, void* d_ws, size_t ws_size,
                              hipStream_t stream)
{
    const float* desc  = (const float*)d_in[0];
    const float* grad  = (const float*)d_in[1];
    const int*   gidx  = (const int*)  d_in[2];
    const float* pos   = (const float*)d_in[3];
    const int*   Zp    = (const int*)  d_in[4];
    const float* box   = (const float*)d_in[5];
    const float* amask = (const float*)d_in[6];
    const float* nmask = (const float*)d_in[7];
    const float* W0    = (const float*)d_in[8];
    const float* b0    = (const float*)d_in[9];
    const float* W1    = (const float*)d_in[10];
    // d_in[11] = b1 (unused by reference)
    const float* W0p   = (const float*)d_in[12];
    const float* b0p   = (const float*)d_in[13];
    const float* W1p   = (const float*)d_in[14];
    const float* b1p   = (const float*)d_in[15];
    float* out = (float*)d_out;
    float* ws  = (float*)d_ws;

    if (ws_size >= (size_t)WS_FLOATS * sizeof(float)) {
        tnep_main<<<NA, 256, 0, stream>>>(desc, grad, gidx, pos, Zp, box, amask, nmask,
                                          W0, b0, W1, W0p, b0p, W1p, b1p, ws);
        tnep_reduce<<<1, 640, 0, stream>>>(ws, out);
    } else {
        tnep_zero<<<1, 64, 0, stream>>>(out);
        tnep_mono<<<NA, 64, 0, stream>>>(desc, grad, gidx, pos, Zp, box, amask, nmask,
                                         W0, b0, W1, W0p, b0p, W1p, b1p, out);
    }
}